// Round 1
// baseline (2708.436 us; speedup 1.0000x reference)
//
#include <hip/hip_runtime.h>
#include <math.h>

#define N_ 4
#define C_ 128
#define H_ 256
#define W_ 256
#define HW_ (H_*W_)
#define BN_EPS 1e-5f

// ---------------- prep: reorder weights to [k][c_out] contiguous ----------------
__global__ __launch_bounds__(256) void k_prep(const float* __restrict__ refine_w,
                                              const float* __restrict__ joint_w,
                                              float* __restrict__ rwr,
                                              float* __restrict__ jwr) {
    int i = blockIdx.x * 256 + threadIdx.x;
    if (i < 128 * 256) {                 // refine_w [co][i2] -> rwr [i2][co]
        int co = i / 256, i2 = i % 256;
        rwr[i2 * 128 + co] = refine_w[i];
    }
    if (i < 128 * 128 * 9) {             // joint_w [co][ci][t] -> jwr [ci*9+t][co]
        int co = i / 1152;
        int r = i % 1152;
        int ci = r / 9, t = r % 9;
        jwr[(ci * 9 + t) * 128 + co] = joint_w[i];
    }
}

// ---------------- kernel 1: dyn_kernel = L1-normalized conv(ms; C->9) ----------------
__global__ __launch_bounds__(256) void k_dyn(const float* __restrict__ ms,
                                             const float* __restrict__ dyn_w,
                                             const float* __restrict__ dyn_b,
                                             float* __restrict__ dk) {
    __shared__ float ms_s[8 * 18 * 18];
    int tid = threadIdx.x;
    int tx = tid & 15, ty = tid >> 4;
    int n = blockIdx.z;
    int h0 = blockIdx.y * 16, w0 = blockIdx.x * 16;
    float acc[9];
#pragma unroll
    for (int k = 0; k < 9; k++) acc[k] = dyn_b[k];

    for (int cc = 0; cc < 16; cc++) {
        __syncthreads();
        for (int e = tid; e < 8 * 18 * 18; e += 256) {
            int ch = e / 324, r = (e % 324) / 18, cl = e % 18;
            int gh = h0 + r - 1, gw = w0 + cl - 1;
            float v = 0.f;
            if (gh >= 0 && gh < H_ && gw >= 0 && gw < W_)
                v = ms[(size_t)(n * C_ + cc * 8 + ch) * HW_ + gh * W_ + gw];
            ms_s[e] = v;
        }
        __syncthreads();
        for (int c8 = 0; c8 < 8; c8++) {
            int c = cc * 8 + c8;
            float m[9];
#pragma unroll
            for (int dy = 0; dy < 3; dy++)
#pragma unroll
                for (int dx = 0; dx < 3; dx++)
                    m[dy * 3 + dx] = ms_s[c8 * 324 + (ty + dy) * 18 + tx + dx];
#pragma unroll
            for (int k = 0; k < 9; k++) {
#pragma unroll
                for (int t = 0; t < 9; t++)
                    acc[k] += m[t] * dyn_w[(k * C_ + c) * 9 + t];
            }
        }
    }
    float s = 0.f;
#pragma unroll
    for (int k = 0; k < 9; k++) s += fabsf(acc[k]);
    float inv = 1.f / s;
    int h = h0 + ty, w = w0 + tx;
#pragma unroll
    for (int k = 0; k < 9; k++)
        dk[(size_t)(n * 9 + k) * HW_ + h * W_ + w] = acc[k] * inv;
}

// ---------------- kernel 2: fused = refine_1x1(concat(dyn_ms, fix_ms)) ----------------
__global__ __launch_bounds__(256) void k_fused(const float* __restrict__ ms,
                                               const float* __restrict__ dk,
                                               const float* __restrict__ fix_w,
                                               const float* __restrict__ bn1_g,
                                               const float* __restrict__ bn1_b,
                                               const float* __restrict__ bn1_m,
                                               const float* __restrict__ bn1_v,
                                               const float* __restrict__ bn2_g,
                                               const float* __restrict__ bn2_b,
                                               const float* __restrict__ bn2_m,
                                               const float* __restrict__ bn2_v,
                                               const float* __restrict__ rwr,
                                               const float* __restrict__ refine_b,
                                               float* __restrict__ fused) {
    __shared__ float act_s[256 * 64];   // [2C][px]  dyn: 0..127, fix: 128..255
    __shared__ float ms_s[8 * 10 * 10];
    __shared__ float dk_s[9 * 64];
    int tid = threadIdx.x;
    int n = blockIdx.z;
    int h0 = blockIdx.y * 8, w0 = blockIdx.x * 8;

    for (int e = tid; e < 9 * 64; e += 256) {
        int t = e / 64, px = e % 64;
        dk_s[e] = dk[(size_t)(n * 9 + t) * HW_ + (h0 + (px >> 3)) * W_ + (w0 + (px & 7))];
    }
    int px = tid & 63;
    int pyy = px >> 3, pxx = px & 7;

    for (int cc = 0; cc < 16; cc++) {
        __syncthreads();
        for (int e = tid; e < 800; e += 256) {
            int ch = e / 100, r = (e % 100) / 10, cl = e % 10;
            int gh = h0 + r - 1, gw = w0 + cl - 1;
            float v = 0.f;
            if (gh >= 0 && gh < H_ && gw >= 0 && gw < W_)
                v = ms[(size_t)(n * C_ + cc * 8 + ch) * HW_ + gh * W_ + gw];
            ms_s[e] = v;
        }
        __syncthreads();
#pragma unroll
        for (int j = 0; j < 2; j++) {
            int ch8 = (tid >> 6) + 4 * j;
            int c = cc * 8 + ch8;
            float m[9];
#pragma unroll
            for (int dy = 0; dy < 3; dy++)
#pragma unroll
                for (int dx = 0; dx < 3; dx++)
                    m[dy * 3 + dx] = ms_s[ch8 * 100 + (pyy + dy) * 10 + pxx + dx];
            float dyn = 0.f, fix = 0.f;
#pragma unroll
            for (int t = 0; t < 9; t++) {
                dyn += m[t] * dk_s[t * 64 + px];
                fix += m[t] * fix_w[c * 9 + t];
            }
            float i1 = bn1_g[c] * rsqrtf(bn1_v[c] + BN_EPS);
            fix = fmaxf(fix * i1 + (bn1_b[c] - bn1_m[c] * i1), 0.f);
            float i2 = bn2_g[c] * rsqrtf(bn2_v[c] + BN_EPS);
            dyn = fmaxf(dyn * i2 + (bn2_b[c] - bn2_m[c] * i2), 0.f);
            act_s[c * 64 + px] = dyn;
            act_s[(C_ + c) * 64 + px] = fix;
        }
    }
    __syncthreads();

    int cg = __builtin_amdgcn_readfirstlane(tid >> 6);
    float acc[32];
#pragma unroll
    for (int j = 0; j < 32; j++) acc[j] = 0.f;
    for (int i = 0; i < 256; i++) {
        float av = act_s[i * 64 + px];
        const float* wrow = &rwr[i * 128 + cg * 32];
#pragma unroll
        for (int j = 0; j < 32; j++)
            acc[j] += av * wrow[j];
    }
    int h = h0 + pyy, w = w0 + pxx;
#pragma unroll
    for (int j = 0; j < 32; j++) {
        int c = cg * 32 + j;
        fused[(size_t)(n * C_ + c) * HW_ + h * W_ + w] = acc[j] + refine_b[c];
    }
}

// ---------------- kernel 3: out = gate(sigmoid(conv3x3(coef+fused))) ----------------
__global__ __launch_bounds__(256) void k_out(const float* __restrict__ coef,
                                             const float* __restrict__ fused,
                                             const float* __restrict__ jwr,
                                             const float* __restrict__ joint_b,
                                             float* __restrict__ out) {
    __shared__ float p_s[128 * 100];    // [ci][10][10]
    int tid = threadIdx.x;
    int n = blockIdx.z;
    int h0 = blockIdx.y * 8, w0 = blockIdx.x * 8;

    for (int e = tid; e < 12800; e += 256) {
        int ci = e / 100, r = (e % 100) / 10, cl = e % 10;
        int gh = h0 + r - 1, gw = w0 + cl - 1;
        float v = 0.f;
        if (gh >= 0 && gh < H_ && gw >= 0 && gw < W_) {
            size_t idx = (size_t)(n * C_ + ci) * HW_ + gh * W_ + gw;
            v = coef[idx] + fused[idx];
        }
        p_s[e] = v;
    }
    __syncthreads();

    int px = tid & 63, py = px >> 3, pxx = px & 7;
    int cg = __builtin_amdgcn_readfirstlane(tid >> 6);
    float acc[32];
#pragma unroll
    for (int j = 0; j < 32; j++) acc[j] = 0.f;

    for (int ci = 0; ci < 128; ci++) {
        float pv[9];
#pragma unroll
        for (int dy = 0; dy < 3; dy++)
#pragma unroll
            for (int dx = 0; dx < 3; dx++)
                pv[dy * 3 + dx] = p_s[ci * 100 + (py + dy) * 10 + pxx + dx];
#pragma unroll
        for (int t = 0; t < 9; t++) {
            const float* wrow = &jwr[(ci * 9 + t) * 128 + cg * 32];
#pragma unroll
            for (int j = 0; j < 32; j++)
                acc[j] += pv[t] * wrow[j];
        }
    }

    int h = h0 + py, w = w0 + pxx;
#pragma unroll
    for (int j = 0; j < 32; j++) {
        int c = cg * 32 + j;
        size_t idx = (size_t)(n * C_ + c) * HW_ + h * W_ + w;
        float z = acc[j] + joint_b[c];
        float p2 = 1.f / (1.f + __expf(-z));
        float f = fused[idx], cf = coef[idx];
        out[idx] = f + p2 * (cf - f);
    }
}

extern "C" void kernel_launch(void* const* d_in, const int* in_sizes, int n_in,
                              void* d_out, int out_size, void* d_ws, size_t ws_size,
                              hipStream_t stream) {
    const float* coef     = (const float*)d_in[0];
    const float* ms       = (const float*)d_in[1];
    const float* fix_w    = (const float*)d_in[2];
    const float* bn1_g    = (const float*)d_in[3];
    const float* bn1_b    = (const float*)d_in[4];
    const float* bn1_m    = (const float*)d_in[5];
    const float* bn1_v    = (const float*)d_in[6];
    const float* dyn_w    = (const float*)d_in[7];
    const float* dyn_b    = (const float*)d_in[8];
    const float* bn2_g    = (const float*)d_in[9];
    const float* bn2_b    = (const float*)d_in[10];
    const float* bn2_m    = (const float*)d_in[11];
    const float* bn2_v    = (const float*)d_in[12];
    const float* refine_w = (const float*)d_in[13];
    const float* refine_b = (const float*)d_in[14];
    const float* joint_w  = (const float*)d_in[15];
    const float* joint_b  = (const float*)d_in[16];
    float* out = (float*)d_out;

    float* ws    = (float*)d_ws;
    float* fused = ws;                        // 33554432 floats
    float* dk    = fused + (size_t)N_ * C_ * HW_;   // 2359296 floats
    float* rwr   = dk + (size_t)N_ * 9 * HW_;       // 32768 floats
    float* jwr   = rwr + 128 * 256;                 // 147456 floats

    dim3 blk(256);
    k_prep<<<dim3((147456 + 255) / 256), blk, 0, stream>>>(refine_w, joint_w, rwr, jwr);
    k_dyn<<<dim3(16, 16, 4), blk, 0, stream>>>(ms, dyn_w, dyn_b, dk);
    k_fused<<<dim3(32, 32, 4), blk, 0, stream>>>(ms, dk, fix_w,
                                                 bn1_g, bn1_b, bn1_m, bn1_v,
                                                 bn2_g, bn2_b, bn2_m, bn2_v,
                                                 rwr, refine_b, fused);
    k_out<<<dim3(32, 32, 4), blk, 0, stream>>>(coef, fused, jwr, joint_b, out);
}

// Round 2
// 1461.333 us; speedup vs baseline: 1.8534x; 1.8534x over previous
//
#include <hip/hip_runtime.h>
#include <hip/hip_bf16.h>
#include <math.h>

#define N_ 4
#define C_ 128
#define H_ 256
#define W_ 256
#define HW_ (H_*W_)
#define BN_EPS 1e-5f

typedef __attribute__((ext_vector_type(8))) short bf16x8;
typedef __attribute__((ext_vector_type(4))) float floatx4;

__device__ __forceinline__ short f2bf(float v) {
    __hip_bfloat16 h = __float2bfloat16(v);
    return __builtin_bit_cast(short, h);
}

// ---------------- prep: rwr for k_fused; jwf = joint_w in MFMA A-frag order (bf16) ----------------
// jwf bf16 flat index: (((t*4 + cic)*8 + cotile)*64 + lane)*8 + j
//   holds W[co = cotile*16 + (lane&15)][ci = cic*32 + (lane>>4)*8 + j] for tap t
__global__ __launch_bounds__(256) void k_prep(const float* __restrict__ refine_w,
                                              const float* __restrict__ joint_w,
                                              float* __restrict__ rwr,
                                              short* __restrict__ jwf) {
    int i = blockIdx.x * 256 + threadIdx.x;
    if (i < 128 * 256) {                 // refine_w [co][i2] -> rwr [i2][co]
        int co = i / 256, i2 = i % 256;
        rwr[i2 * 128 + co] = refine_w[i];
    }
    if (i < 147456) {
        int j      = i & 7;
        int lane   = (i >> 3) & 63;
        int cotile = (i >> 9) & 7;
        int cic    = (i >> 12) & 3;
        int t      = i >> 14;            // 0..8
        int co = cotile * 16 + (lane & 15);
        int ci = cic * 32 + (lane >> 4) * 8 + j;
        jwf[i] = f2bf(joint_w[(co * 128 + ci) * 9 + t]);
    }
}

// ---------------- kernel 1: dyn_kernel = L1-normalized conv(ms; C->9) ----------------
__global__ __launch_bounds__(256) void k_dyn(const float* __restrict__ ms,
                                             const float* __restrict__ dyn_w,
                                             const float* __restrict__ dyn_b,
                                             float* __restrict__ dk) {
    __shared__ float ms_s[8 * 18 * 18];
    int tid = threadIdx.x;
    int tx = tid & 15, ty = tid >> 4;
    int n = blockIdx.z;
    int h0 = blockIdx.y * 16, w0 = blockIdx.x * 16;
    float acc[9];
#pragma unroll
    for (int k = 0; k < 9; k++) acc[k] = dyn_b[k];

    for (int cc = 0; cc < 16; cc++) {
        __syncthreads();
        for (int e = tid; e < 8 * 18 * 18; e += 256) {
            int ch = e / 324, r = (e % 324) / 18, cl = e % 18;
            int gh = h0 + r - 1, gw = w0 + cl - 1;
            float v = 0.f;
            if (gh >= 0 && gh < H_ && gw >= 0 && gw < W_)
                v = ms[(size_t)(n * C_ + cc * 8 + ch) * HW_ + gh * W_ + gw];
            ms_s[e] = v;
        }
        __syncthreads();
        for (int c8 = 0; c8 < 8; c8++) {
            int c = cc * 8 + c8;
            float m[9];
#pragma unroll
            for (int dy = 0; dy < 3; dy++)
#pragma unroll
                for (int dx = 0; dx < 3; dx++)
                    m[dy * 3 + dx] = ms_s[c8 * 324 + (ty + dy) * 18 + tx + dx];
#pragma unroll
            for (int k = 0; k < 9; k++) {
#pragma unroll
                for (int t = 0; t < 9; t++)
                    acc[k] += m[t] * dyn_w[(k * C_ + c) * 9 + t];
            }
        }
    }
    float s = 0.f;
#pragma unroll
    for (int k = 0; k < 9; k++) s += fabsf(acc[k]);
    float inv = 1.f / s;
    int h = h0 + ty, w = w0 + tx;
#pragma unroll
    for (int k = 0; k < 9; k++)
        dk[(size_t)(n * 9 + k) * HW_ + h * W_ + w] = acc[k] * inv;
}

// ---------------- kernel 2: fused = refine_1x1(concat(dyn_ms, fix_ms)) ----------------
__global__ __launch_bounds__(256) void k_fused(const float* __restrict__ ms,
                                               const float* __restrict__ dk,
                                               const float* __restrict__ fix_w,
                                               const float* __restrict__ bn1_g,
                                               const float* __restrict__ bn1_b,
                                               const float* __restrict__ bn1_m,
                                               const float* __restrict__ bn1_v,
                                               const float* __restrict__ bn2_g,
                                               const float* __restrict__ bn2_b,
                                               const float* __restrict__ bn2_m,
                                               const float* __restrict__ bn2_v,
                                               const float* __restrict__ rwr,
                                               const float* __restrict__ refine_b,
                                               float* __restrict__ fused) {
    __shared__ float act_s[256 * 64];   // [2C][px]  dyn: 0..127, fix: 128..255
    __shared__ float ms_s[8 * 10 * 10];
    __shared__ float dk_s[9 * 64];
    int tid = threadIdx.x;
    int n = blockIdx.z;
    int h0 = blockIdx.y * 8, w0 = blockIdx.x * 8;

    for (int e = tid; e < 9 * 64; e += 256) {
        int t = e / 64, px = e % 64;
        dk_s[e] = dk[(size_t)(n * 9 + t) * HW_ + (h0 + (px >> 3)) * W_ + (w0 + (px & 7))];
    }
    int px = tid & 63;
    int pyy = px >> 3, pxx = px & 7;

    for (int cc = 0; cc < 16; cc++) {
        __syncthreads();
        for (int e = tid; e < 800; e += 256) {
            int ch = e / 100, r = (e % 100) / 10, cl = e % 10;
            int gh = h0 + r - 1, gw = w0 + cl - 1;
            float v = 0.f;
            if (gh >= 0 && gh < H_ && gw >= 0 && gw < W_)
                v = ms[(size_t)(n * C_ + cc * 8 + ch) * HW_ + gh * W_ + gw];
            ms_s[e] = v;
        }
        __syncthreads();
#pragma unroll
        for (int j = 0; j < 2; j++) {
            int ch8 = (tid >> 6) + 4 * j;
            int c = cc * 8 + ch8;
            float m[9];
#pragma unroll
            for (int dy = 0; dy < 3; dy++)
#pragma unroll
                for (int dx = 0; dx < 3; dx++)
                    m[dy * 3 + dx] = ms_s[ch8 * 100 + (pyy + dy) * 10 + pxx + dx];
            float dyn = 0.f, fix = 0.f;
#pragma unroll
            for (int t = 0; t < 9; t++) {
                dyn += m[t] * dk_s[t * 64 + px];
                fix += m[t] * fix_w[c * 9 + t];
            }
            float i1 = bn1_g[c] * rsqrtf(bn1_v[c] + BN_EPS);
            fix = fmaxf(fix * i1 + (bn1_b[c] - bn1_m[c] * i1), 0.f);
            float i2 = bn2_g[c] * rsqrtf(bn2_v[c] + BN_EPS);
            dyn = fmaxf(dyn * i2 + (bn2_b[c] - bn2_m[c] * i2), 0.f);
            act_s[c * 64 + px] = dyn;
            act_s[(C_ + c) * 64 + px] = fix;
        }
    }
    __syncthreads();

    int cg = __builtin_amdgcn_readfirstlane(tid >> 6);
    float acc[32];
#pragma unroll
    for (int j = 0; j < 32; j++) acc[j] = 0.f;
    for (int i = 0; i < 256; i++) {
        float av = act_s[i * 64 + px];
        const float* wrow = &rwr[i * 128 + cg * 32];
#pragma unroll
        for (int j = 0; j < 32; j++)
            acc[j] += av * wrow[j];
    }
    int h = h0 + pyy, w = w0 + pxx;
#pragma unroll
    for (int j = 0; j < 32; j++) {
        int c = cg * 32 + j;
        fused[(size_t)(n * C_ + c) * HW_ + h * W_ + w] = acc[j] + refine_b[c];
    }
}

// ---------------- kernel 3 (MFMA): out = gate(sigmoid(conv3x3(coef+fused))) ----------------
// Block: 8 rows x 16 cols of pixels, all 128 c_out. GEMM D[co][px] as 9 shifted
// 1x1 GEMMs over the LDS p-tile. bf16 inputs, fp32 MFMA accumulate.
#define CIP 136   // ci leading-dim pad: 136*2B = 17 granules of 16B -> conflict-free b128
__global__ __launch_bounds__(256, 3) void k_out(const float* __restrict__ coef,
                                                const float* __restrict__ fused,
                                                const short* __restrict__ jwf,
                                                const float* __restrict__ joint_b,
                                                float* __restrict__ out) {
    __shared__ short p_s[180 * CIP];    // [(row*18+col)][ci], rows 10, cols 18
    int tid = threadIdx.x;
    int n = blockIdx.z;
    int h0 = blockIdx.y * 8, w0 = blockIdx.x * 16;

    // stage p = coef + fused (bf16) — e = ci*180 + sp so consecutive lanes read consecutive gw
    for (int it = 0; it < 90; it++) {
        int e = tid + it * 256;
        int ci = e / 180, sp = e - ci * 180;
        int row = sp / 18, col = sp - row * 18;
        int gh = h0 + row - 1, gw = w0 + col - 1;
        float v = 0.f;
        if (gh >= 0 && gh < H_ && gw >= 0 && gw < W_) {
            size_t idx = (size_t)(n * C_ + ci) * HW_ + gh * W_ + gw;
            v = coef[idx] + fused[idx];
        }
        p_s[sp * CIP + ci] = f2bf(v);
    }
    __syncthreads();

    int lane = tid & 63;
    int wave = __builtin_amdgcn_readfirstlane(tid >> 6);
    int c = lane & 15;        // px column within 16-wide tile
    int q = lane >> 4;        // quad
    int py0 = wave;           // this wave's two pixel rows
    int py1 = wave + 4;

    floatx4 acc[8][2];
#pragma unroll
    for (int ct = 0; ct < 8; ct++)
#pragma unroll
        for (int p = 0; p < 2; p++)
            acc[ct][p] = (floatx4){0.f, 0.f, 0.f, 0.f};

    const bf16x8* jwv = (const bf16x8*)jwf;   // frag index: (t*4+cic)*8*64 + cotile*64 + lane

    for (int t = 0; t < 9; t++) {
        int dy = t / 3, dx = t - dy * 3;
        int sb0 = ((py0 + dy) * 18 + c + dx) * CIP + q * 8;
        int sb1 = ((py1 + dy) * 18 + c + dx) * CIP + q * 8;
#pragma unroll
        for (int cic = 0; cic < 4; cic++) {
            bf16x8 B0 = *(const bf16x8*)(p_s + sb0 + cic * 32);
            bf16x8 B1 = *(const bf16x8*)(p_s + sb1 + cic * 32);
            const bf16x8* Ap = jwv + ((t * 4 + cic) * 8) * 64 + lane;
            bf16x8 A[8];
#pragma unroll
            for (int ct = 0; ct < 8; ct++) A[ct] = Ap[ct * 64];
#pragma unroll
            for (int ct = 0; ct < 8; ct++) {
                acc[ct][0] = __builtin_amdgcn_mfma_f32_16x16x32_bf16(A[ct], B0, acc[ct][0], 0, 0, 0);
                acc[ct][1] = __builtin_amdgcn_mfma_f32_16x16x32_bf16(A[ct], B1, acc[ct][1], 0, 0, 0);
            }
        }
    }

    // epilogue: D lane mapping col = lane&15 (px), row = q*4 + r (co within tile)
    int w = w0 + c;
#pragma unroll
    for (int ct = 0; ct < 8; ct++) {
#pragma unroll
        for (int p = 0; p < 2; p++) {
            int h = h0 + (p == 0 ? py0 : py1);
#pragma unroll
            for (int r = 0; r < 4; r++) {
                int co = ct * 16 + q * 4 + r;
                size_t idx = (size_t)(n * C_ + co) * HW_ + h * W_ + w;
                float z = acc[ct][p][r] + joint_b[co];
                float p2 = 1.f / (1.f + __expf(-z));
                float f = fused[idx], cf = coef[idx];
                out[idx] = f + p2 * (cf - f);
            }
        }
    }
}

extern "C" void kernel_launch(void* const* d_in, const int* in_sizes, int n_in,
                              void* d_out, int out_size, void* d_ws, size_t ws_size,
                              hipStream_t stream) {
    const float* coef     = (const float*)d_in[0];
    const float* ms       = (const float*)d_in[1];
    const float* fix_w    = (const float*)d_in[2];
    const float* bn1_g    = (const float*)d_in[3];
    const float* bn1_b    = (const float*)d_in[4];
    const float* bn1_m    = (const float*)d_in[5];
    const float* bn1_v    = (const float*)d_in[6];
    const float* dyn_w    = (const float*)d_in[7];
    const float* dyn_b    = (const float*)d_in[8];
    const float* bn2_g    = (const float*)d_in[9];
    const float* bn2_b    = (const float*)d_in[10];
    const float* bn2_m    = (const float*)d_in[11];
    const float* bn2_v    = (const float*)d_in[12];
    const float* refine_w = (const float*)d_in[13];
    const float* refine_b = (const float*)d_in[14];
    const float* joint_w  = (const float*)d_in[15];
    const float* joint_b  = (const float*)d_in[16];
    float* out = (float*)d_out;

    float* ws    = (float*)d_ws;
    float* fused = ws;                              // 33554432 floats
    float* dk    = fused + (size_t)N_ * C_ * HW_;   // 2359296 floats
    float* rwr   = dk + (size_t)N_ * 9 * HW_;       // 32768 floats
    short* jwf   = (short*)(rwr + 128 * 256);       // 147456 bf16

    dim3 blk(256);
    k_prep<<<dim3(576), blk, 0, stream>>>(refine_w, joint_w, rwr, jwf);
    k_dyn<<<dim3(16, 16, 4), blk, 0, stream>>>(ms, dyn_w, dyn_b, dk);
    k_fused<<<dim3(32, 32, 4), blk, 0, stream>>>(ms, dk, fix_w,
                                                 bn1_g, bn1_b, bn1_m, bn1_v,
                                                 bn2_g, bn2_b, bn2_m, bn2_v,
                                                 rwr, refine_b, fused);
    k_out<<<dim3(16, 32, 4), blk, 0, stream>>>(coef, fused, jwf, joint_b, out);
}

// Round 3
// 1067.562 us; speedup vs baseline: 2.5370x; 1.3689x over previous
//
#include <hip/hip_runtime.h>
#include <hip/hip_bf16.h>
#include <math.h>

#define N_ 4
#define C_ 128
#define H_ 256
#define W_ 256
#define HW_ (H_*W_)
#define BN_EPS 1e-5f

typedef __attribute__((ext_vector_type(8))) short bf16x8;
typedef __attribute__((ext_vector_type(4))) float floatx4;

__device__ __forceinline__ short f2bf(float v) {
    __hip_bfloat16 h = __float2bfloat16(v);
    return __builtin_bit_cast(short, h);
}

// ---------------- prep: weight swizzles into MFMA A-frag order (bf16) ----------------
// jwf: (((t*4 + cic)*8 + cotile)*64 + lane)*8 + j = W_joint[co=cotile*16+(lane&15)][ci=cic*32+(lane>>4)*8+j][t]
// rwf: (((cic*8) + cotile)*64 + lane)*8 + j      = W_refine[co=cotile*16+(lane&15)][i=cic*32+(lane>>4)*8+j]
__global__ __launch_bounds__(256) void k_prep(const float* __restrict__ refine_w,
                                              const float* __restrict__ joint_w,
                                              short* __restrict__ rwf,
                                              short* __restrict__ jwf) {
    int i = blockIdx.x * 256 + threadIdx.x;
    if (i < 32768) {
        int j      = i & 7;
        int lane   = (i >> 3) & 63;
        int cotile = (i >> 9) & 7;
        int cic    = (i >> 12) & 7;
        int co = cotile * 16 + (lane & 15);
        int ii = cic * 32 + (lane >> 4) * 8 + j;
        rwf[i] = f2bf(refine_w[co * 256 + ii]);
    }
    if (i < 147456) {
        int j      = i & 7;
        int lane   = (i >> 3) & 63;
        int cotile = (i >> 9) & 7;
        int cic    = (i >> 12) & 3;
        int t      = i >> 14;            // 0..8
        int co = cotile * 16 + (lane & 15);
        int ci = cic * 32 + (lane >> 4) * 8 + j;
        jwf[i] = f2bf(joint_w[(co * 128 + ci) * 9 + t]);
    }
}

// ---------------- kernel 1: dyn_kernel = L1-normalized conv(ms; C->9) ----------------
__global__ __launch_bounds__(256) void k_dyn(const float* __restrict__ ms,
                                             const float* __restrict__ dyn_w,
                                             const float* __restrict__ dyn_b,
                                             float* __restrict__ dk) {
    __shared__ float ms_s[8 * 18 * 18];
    int tid = threadIdx.x;
    int tx = tid & 15, ty = tid >> 4;
    int n = blockIdx.z;
    int h0 = blockIdx.y * 16, w0 = blockIdx.x * 16;
    float acc[9];
#pragma unroll
    for (int k = 0; k < 9; k++) acc[k] = dyn_b[k];

    for (int cc = 0; cc < 16; cc++) {
        __syncthreads();
        for (int e = tid; e < 8 * 18 * 18; e += 256) {
            int ch = e / 324, r = (e % 324) / 18, cl = e % 18;
            int gh = h0 + r - 1, gw = w0 + cl - 1;
            float v = 0.f;
            if (gh >= 0 && gh < H_ && gw >= 0 && gw < W_)
                v = ms[(size_t)(n * C_ + cc * 8 + ch) * HW_ + gh * W_ + gw];
            ms_s[e] = v;
        }
        __syncthreads();
        for (int c8 = 0; c8 < 8; c8++) {
            int c = cc * 8 + c8;
            float m[9];
#pragma unroll
            for (int dy = 0; dy < 3; dy++)
#pragma unroll
                for (int dx = 0; dx < 3; dx++)
                    m[dy * 3 + dx] = ms_s[c8 * 324 + (ty + dy) * 18 + tx + dx];
#pragma unroll
            for (int k = 0; k < 9; k++) {
#pragma unroll
                for (int t = 0; t < 9; t++)
                    acc[k] += m[t] * dyn_w[(k * C_ + c) * 9 + t];
            }
        }
    }
    float s = 0.f;
#pragma unroll
    for (int k = 0; k < 9; k++) s += fabsf(acc[k]);
    float inv = 1.f / s;
    int h = h0 + ty, w = w0 + tx;
#pragma unroll
    for (int k = 0; k < 9; k++)
        dk[(size_t)(n * 9 + k) * HW_ + h * W_ + w] = acc[k] * inv;
}

// ---------------- kernel 2 (MFMA): fused = refine_1x1(concat(dyn_ms, fix_ms)) ----------------
// 8x8 px tile, all 128 co. act_s bf16 [px][i], i in 0..255 (dyn 0..127, fix 128..255),
// i-stride 264 (33 granules, odd -> conflict-free b128 reads).
#define AIP 264
__global__ __launch_bounds__(256) void k_fused(const float* __restrict__ ms,
                                               const float* __restrict__ dk,
                                               const float* __restrict__ fix_w,
                                               const float* __restrict__ bn1_g,
                                               const float* __restrict__ bn1_b,
                                               const float* __restrict__ bn1_m,
                                               const float* __restrict__ bn1_v,
                                               const float* __restrict__ bn2_g,
                                               const float* __restrict__ bn2_b,
                                               const float* __restrict__ bn2_m,
                                               const float* __restrict__ bn2_v,
                                               const short* __restrict__ rwf,
                                               const float* __restrict__ refine_b,
                                               float* __restrict__ fused) {
    __shared__ short act_s[64 * AIP];
    __shared__ float ms_s[8 * 100];
    __shared__ float dk_s[9 * 64];
    int tid = threadIdx.x;
    int n = blockIdx.z;
    int h0 = blockIdx.y * 8, w0 = blockIdx.x * 8;

    for (int e = tid; e < 9 * 64; e += 256) {
        int t = e >> 6, px = e & 63;
        dk_s[e] = dk[(size_t)(n * 9 + t) * HW_ + (h0 + (px >> 3)) * W_ + (w0 + (px & 7))];
    }

    int c8 = tid & 7;
    int pxh = tid >> 3;          // 0..31

    for (int cc = 0; cc < 16; cc++) {
        __syncthreads();
        for (int e = tid; e < 800; e += 256) {
            int ch = e / 100, r = (e % 100) / 10, cl = e % 10;
            int gh = h0 + r - 1, gw = w0 + cl - 1;
            float v = 0.f;
            if (gh >= 0 && gh < H_ && gw >= 0 && gw < W_)
                v = ms[(size_t)(n * C_ + cc * 8 + ch) * HW_ + gh * W_ + gw];
            ms_s[e] = v;
        }
        __syncthreads();
        int c = cc * 8 + c8;
        float i1 = bn1_g[c] * rsqrtf(bn1_v[c] + BN_EPS);
        float b1 = bn1_b[c] - bn1_m[c] * i1;
        float i2 = bn2_g[c] * rsqrtf(bn2_v[c] + BN_EPS);
        float b2 = bn2_b[c] - bn2_m[c] * i2;
        float fw[9];
#pragma unroll
        for (int t = 0; t < 9; t++) fw[t] = fix_w[c * 9 + t];
#pragma unroll
        for (int it = 0; it < 2; it++) {
            int px = pxh + it * 32;
            int py = px >> 3, pxx = px & 7;
            float m[9];
#pragma unroll
            for (int dy = 0; dy < 3; dy++)
#pragma unroll
                for (int dx = 0; dx < 3; dx++)
                    m[dy * 3 + dx] = ms_s[c8 * 100 + (py + dy) * 10 + pxx + dx];
            float dyn = 0.f, fix = 0.f;
#pragma unroll
            for (int t = 0; t < 9; t++) {
                dyn += m[t] * dk_s[t * 64 + px];
                fix += m[t] * fw[t];
            }
            dyn = fmaxf(dyn * i2 + b2, 0.f);
            fix = fmaxf(fix * i1 + b1, 0.f);
            act_s[px * AIP + c] = f2bf(dyn);
            act_s[px * AIP + 128 + c] = f2bf(fix);
        }
    }
    __syncthreads();

    // GEMM: D[co][px] = rwf x act, K=256
    int lane = tid & 63;
    int wave = __builtin_amdgcn_readfirstlane(tid >> 6);
    int cl16 = lane & 15;
    int q = lane >> 4;
    int pxb = wave * 16;

    floatx4 acc[8];
#pragma unroll
    for (int ct = 0; ct < 8; ct++) acc[ct] = (floatx4){0.f, 0.f, 0.f, 0.f};

    const bf16x8* rwv = (const bf16x8*)rwf;
#pragma unroll
    for (int cic = 0; cic < 8; cic++) {
        bf16x8 B = *(const bf16x8*)(act_s + (pxb + cl16) * AIP + q * 8 + cic * 32);
        const bf16x8* Ap = rwv + cic * 8 * 64 + lane;
        bf16x8 A[8];
#pragma unroll
        for (int ct = 0; ct < 8; ct++) A[ct] = Ap[ct * 64];
#pragma unroll
        for (int ct = 0; ct < 8; ct++)
            acc[ct] = __builtin_amdgcn_mfma_f32_16x16x32_bf16(A[ct], B, acc[ct], 0, 0, 0);
    }

    int px = pxb + cl16;
    int h = h0 + (px >> 3), w = w0 + (px & 7);
#pragma unroll
    for (int ct = 0; ct < 8; ct++) {
#pragma unroll
        for (int r = 0; r < 4; r++) {
            int co = ct * 16 + q * 4 + r;
            fused[(size_t)(n * C_ + co) * HW_ + h * W_ + w] = acc[ct][r] + refine_b[co];
        }
    }
}

// ---------------- kernel 3 (MFMA): out = gate(sigmoid(conv3x3(coef+fused))) ----------------
#define CIP 136   // ci leading-dim pad: 136*2B = 17 granules of 16B -> conflict-free b128
__global__ __launch_bounds__(256, 3) void k_out(const float* __restrict__ coef,
                                                const float* __restrict__ fused,
                                                const short* __restrict__ jwf,
                                                const float* __restrict__ joint_b,
                                                float* __restrict__ out) {
    __shared__ short p_s[180 * CIP];    // [(row*18+col)][ci], rows 10, cols 18
    int tid = threadIdx.x;
    int n = blockIdx.z;
    int h0 = blockIdx.y * 8, w0 = blockIdx.x * 16;

    for (int it = 0; it < 90; it++) {
        int e = tid + it * 256;
        int ci = e / 180, sp = e - ci * 180;
        int row = sp / 18, col = sp - row * 18;
        int gh = h0 + row - 1, gw = w0 + col - 1;
        float v = 0.f;
        if (gh >= 0 && gh < H_ && gw >= 0 && gw < W_) {
            size_t idx = (size_t)(n * C_ + ci) * HW_ + gh * W_ + gw;
            v = coef[idx] + fused[idx];
        }
        p_s[sp * CIP + ci] = f2bf(v);
    }
    __syncthreads();

    int lane = tid & 63;
    int wave = __builtin_amdgcn_readfirstlane(tid >> 6);
    int c = lane & 15;
    int q = lane >> 4;
    int py0 = wave;
    int py1 = wave + 4;

    floatx4 acc[8][2];
#pragma unroll
    for (int ct = 0; ct < 8; ct++)
#pragma unroll
        for (int p = 0; p < 2; p++)
            acc[ct][p] = (floatx4){0.f, 0.f, 0.f, 0.f};

    const bf16x8* jwv = (const bf16x8*)jwf;

    for (int t = 0; t < 9; t++) {
        int dy = t / 3, dx = t - dy * 3;
        int sb0 = ((py0 + dy) * 18 + c + dx) * CIP + q * 8;
        int sb1 = ((py1 + dy) * 18 + c + dx) * CIP + q * 8;
#pragma unroll
        for (int cic = 0; cic < 4; cic++) {
            bf16x8 B0 = *(const bf16x8*)(p_s + sb0 + cic * 32);
            bf16x8 B1 = *(const bf16x8*)(p_s + sb1 + cic * 32);
            const bf16x8* Ap = jwv + ((t * 4 + cic) * 8) * 64 + lane;
            bf16x8 A[8];
#pragma unroll
            for (int ct = 0; ct < 8; ct++) A[ct] = Ap[ct * 64];
#pragma unroll
            for (int ct = 0; ct < 8; ct++) {
                acc[ct][0] = __builtin_amdgcn_mfma_f32_16x16x32_bf16(A[ct], B0, acc[ct][0], 0, 0, 0);
                acc[ct][1] = __builtin_amdgcn_mfma_f32_16x16x32_bf16(A[ct], B1, acc[ct][1], 0, 0, 0);
            }
        }
    }

    int w = w0 + c;
#pragma unroll
    for (int ct = 0; ct < 8; ct++) {
#pragma unroll
        for (int p = 0; p < 2; p++) {
            int h = h0 + (p == 0 ? py0 : py1);
#pragma unroll
            for (int r = 0; r < 4; r++) {
                int co = ct * 16 + q * 4 + r;
                size_t idx = (size_t)(n * C_ + co) * HW_ + h * W_ + w;
                float z = acc[ct][p][r] + joint_b[co];
                float p2 = 1.f / (1.f + __expf(-z));
                float f = fused[idx], cf = coef[idx];
                out[idx] = f + p2 * (cf - f);
            }
        }
    }
}

extern "C" void kernel_launch(void* const* d_in, const int* in_sizes, int n_in,
                              void* d_out, int out_size, void* d_ws, size_t ws_size,
                              hipStream_t stream) {
    const float* coef     = (const float*)d_in[0];
    const float* ms       = (const float*)d_in[1];
    const float* fix_w    = (const float*)d_in[2];
    const float* bn1_g    = (const float*)d_in[3];
    const float* bn1_b    = (const float*)d_in[4];
    const float* bn1_m    = (const float*)d_in[5];
    const float* bn1_v    = (const float*)d_in[6];
    const float* dyn_w    = (const float*)d_in[7];
    const float* dyn_b    = (const float*)d_in[8];
    const float* bn2_g    = (const float*)d_in[9];
    const float* bn2_b    = (const float*)d_in[10];
    const float* bn2_m    = (const float*)d_in[11];
    const float* bn2_v    = (const float*)d_in[12];
    const float* refine_w = (const float*)d_in[13];
    const float* refine_b = (const float*)d_in[14];
    const float* joint_w  = (const float*)d_in[15];
    const float* joint_b  = (const float*)d_in[16];
    float* out = (float*)d_out;

    float* ws    = (float*)d_ws;
    float* fused = ws;                              // 33554432 floats
    float* dk    = fused + (size_t)N_ * C_ * HW_;   // 2359296 floats
    short* jwf   = (short*)(dk + (size_t)N_ * 9 * HW_);  // 147456 bf16
    short* rwf   = jwf + 147456;                    // 32768 bf16

    dim3 blk(256);
    k_prep<<<dim3(576), blk, 0, stream>>>(refine_w, joint_w, rwf, jwf);
    k_dyn<<<dim3(16, 16, 4), blk, 0, stream>>>(ms, dyn_w, dyn_b, dk);
    k_fused<<<dim3(32, 32, 4), blk, 0, stream>>>(ms, dk, fix_w,
                                                 bn1_g, bn1_b, bn1_m, bn1_v,
                                                 bn2_g, bn2_b, bn2_m, bn2_v,
                                                 rwf, refine_b, fused);
    k_out<<<dim3(16, 32, 4), blk, 0, stream>>>(coef, fused, jwf, joint_b, out);
}

// Round 4
// 1015.250 us; speedup vs baseline: 2.6678x; 1.0515x over previous
//
#include <hip/hip_runtime.h>
#include <hip/hip_bf16.h>
#include <math.h>

#define N_ 4
#define C_ 128
#define H_ 256
#define W_ 256
#define HW_ (H_*W_)
#define BN_EPS 1e-5f

typedef __attribute__((ext_vector_type(8))) short bf16x8;
typedef __attribute__((ext_vector_type(4))) float floatx4;

__device__ __forceinline__ short f2bf(float v) {
    __hip_bfloat16 h = __float2bfloat16(v);
    return __builtin_bit_cast(short, h);
}
__device__ __forceinline__ float bf2f(short s) {
    unsigned u = ((unsigned)(unsigned short)s) << 16;
    return __builtin_bit_cast(float, u);
}

// ---------------- prep: weight swizzles into MFMA A-frag order (bf16) ----------------
// jwf: (((t*4 + cic)*8 + cotile)*64 + lane)*8 + j = W_joint[co=cotile*16+(lane&15)][ci=cic*32+(lane>>4)*8+j][t]
// rwf: (((cic*8) + cotile)*64 + lane)*8 + j      = W_refine[co=cotile*16+(lane&15)][i=cic*32+(lane>>4)*8+j]
__global__ __launch_bounds__(256) void k_prep(const float* __restrict__ refine_w,
                                              const float* __restrict__ joint_w,
                                              short* __restrict__ rwf,
                                              short* __restrict__ jwf) {
    int i = blockIdx.x * 256 + threadIdx.x;
    if (i < 32768) {
        int j      = i & 7;
        int lane   = (i >> 3) & 63;
        int cotile = (i >> 9) & 7;
        int cic    = (i >> 12) & 7;
        int co = cotile * 16 + (lane & 15);
        int ii = cic * 32 + (lane >> 4) * 8 + j;
        rwf[i] = f2bf(refine_w[co * 256 + ii]);
    }
    if (i < 147456) {
        int j      = i & 7;
        int lane   = (i >> 3) & 63;
        int cotile = (i >> 9) & 7;
        int cic    = (i >> 12) & 3;
        int t      = i >> 14;            // 0..8
        int co = cotile * 16 + (lane & 15);
        int ci = cic * 32 + (lane >> 4) * 8 + j;
        jwf[i] = f2bf(joint_w[(co * 128 + ci) * 9 + t]);
    }
}

// ---------------- kernel 1: dyn_kernel = L1-normalized conv(ms; C->9) ----------------
__global__ __launch_bounds__(256) void k_dyn(const float* __restrict__ ms,
                                             const float* __restrict__ dyn_w,
                                             const float* __restrict__ dyn_b,
                                             float* __restrict__ dk) {
    __shared__ float ms_s[8 * 18 * 18];
    int tid = threadIdx.x;
    int tx = tid & 15, ty = tid >> 4;
    int n = blockIdx.z;
    int h0 = blockIdx.y * 16, w0 = blockIdx.x * 16;
    float acc[9];
#pragma unroll
    for (int k = 0; k < 9; k++) acc[k] = dyn_b[k];

    for (int cc = 0; cc < 16; cc++) {
        __syncthreads();
        for (int e = tid; e < 8 * 18 * 18; e += 256) {
            int ch = e / 324, r = (e % 324) / 18, cl = e % 18;
            int gh = h0 + r - 1, gw = w0 + cl - 1;
            float v = 0.f;
            if (gh >= 0 && gh < H_ && gw >= 0 && gw < W_)
                v = ms[(size_t)(n * C_ + cc * 8 + ch) * HW_ + gh * W_ + gw];
            ms_s[e] = v;
        }
        __syncthreads();
        for (int c8 = 0; c8 < 8; c8++) {
            int c = cc * 8 + c8;
            float m[9];
#pragma unroll
            for (int dy = 0; dy < 3; dy++)
#pragma unroll
                for (int dx = 0; dx < 3; dx++)
                    m[dy * 3 + dx] = ms_s[c8 * 324 + (ty + dy) * 18 + tx + dx];
#pragma unroll
            for (int k = 0; k < 9; k++) {
#pragma unroll
                for (int t = 0; t < 9; t++)
                    acc[k] += m[t] * dyn_w[(k * C_ + c) * 9 + t];
            }
        }
    }
    float s = 0.f;
#pragma unroll
    for (int k = 0; k < 9; k++) s += fabsf(acc[k]);
    float inv = 1.f / s;
    int h = h0 + ty, w = w0 + tx;
#pragma unroll
    for (int k = 0; k < 9; k++)
        dk[(size_t)(n * 9 + k) * HW_ + h * W_ + w] = acc[k] * inv;
}

// ---------------- kernel 2 (MFMA): refine 1x1; emits fusedbf & pbf in NHWC bf16 ----------------
#define AIP 264
__global__ __launch_bounds__(256) void k_fused(const float* __restrict__ ms,
                                               const float* __restrict__ dk,
                                               const float* __restrict__ coef,
                                               const float* __restrict__ fix_w,
                                               const float* __restrict__ bn1_g,
                                               const float* __restrict__ bn1_b,
                                               const float* __restrict__ bn1_m,
                                               const float* __restrict__ bn1_v,
                                               const float* __restrict__ bn2_g,
                                               const float* __restrict__ bn2_b,
                                               const float* __restrict__ bn2_m,
                                               const float* __restrict__ bn2_v,
                                               const short* __restrict__ rwf,
                                               const float* __restrict__ refine_b,
                                               short* __restrict__ fusedbf,
                                               short* __restrict__ pbf) {
    __shared__ short act_s[64 * AIP];
    __shared__ float ms_s[8 * 100];
    __shared__ float dk_s[9 * 64];
    int tid = threadIdx.x;
    int n = blockIdx.z;
    int h0 = blockIdx.y * 8, w0 = blockIdx.x * 8;

    for (int e = tid; e < 9 * 64; e += 256) {
        int t = e >> 6, px = e & 63;
        dk_s[e] = dk[(size_t)(n * 9 + t) * HW_ + (h0 + (px >> 3)) * W_ + (w0 + (px & 7))];
    }

    int c8 = tid & 7;
    int pxh = tid >> 3;          // 0..31

    for (int cc = 0; cc < 16; cc++) {
        __syncthreads();
        for (int e = tid; e < 800; e += 256) {
            int ch = e / 100, r = (e % 100) / 10, cl = e % 10;
            int gh = h0 + r - 1, gw = w0 + cl - 1;
            float v = 0.f;
            if (gh >= 0 && gh < H_ && gw >= 0 && gw < W_)
                v = ms[(size_t)(n * C_ + cc * 8 + ch) * HW_ + gh * W_ + gw];
            ms_s[e] = v;
        }
        __syncthreads();
        int c = cc * 8 + c8;
        float i1 = bn1_g[c] * rsqrtf(bn1_v[c] + BN_EPS);
        float b1 = bn1_b[c] - bn1_m[c] * i1;
        float i2 = bn2_g[c] * rsqrtf(bn2_v[c] + BN_EPS);
        float b2 = bn2_b[c] - bn2_m[c] * i2;
        float fw[9];
#pragma unroll
        for (int t = 0; t < 9; t++) fw[t] = fix_w[c * 9 + t];
#pragma unroll
        for (int it = 0; it < 2; it++) {
            int px = pxh + it * 32;
            int py = px >> 3, pxx = px & 7;
            float m[9];
#pragma unroll
            for (int dy = 0; dy < 3; dy++)
#pragma unroll
                for (int dx = 0; dx < 3; dx++)
                    m[dy * 3 + dx] = ms_s[c8 * 100 + (py + dy) * 10 + pxx + dx];
            float dyn = 0.f, fix = 0.f;
#pragma unroll
            for (int t = 0; t < 9; t++) {
                dyn += m[t] * dk_s[t * 64 + px];
                fix += m[t] * fw[t];
            }
            dyn = fmaxf(dyn * i2 + b2, 0.f);
            fix = fmaxf(fix * i1 + b1, 0.f);
            act_s[px * AIP + c] = f2bf(dyn);
            act_s[px * AIP + 128 + c] = f2bf(fix);
        }
    }
    __syncthreads();

    // GEMM: D[co][px] = rwf x act, K=256
    int lane = tid & 63;
    int wave = __builtin_amdgcn_readfirstlane(tid >> 6);
    int cl16 = lane & 15;
    int q = lane >> 4;
    int pxb = wave * 16;

    floatx4 acc[8];
#pragma unroll
    for (int ct = 0; ct < 8; ct++) acc[ct] = (floatx4){0.f, 0.f, 0.f, 0.f};

    const bf16x8* rwv = (const bf16x8*)rwf;
#pragma unroll
    for (int cic = 0; cic < 8; cic++) {
        bf16x8 B = *(const bf16x8*)(act_s + (pxb + cl16) * AIP + q * 8 + cic * 32);
        const bf16x8* Ap = rwv + cic * 8 * 64 + lane;
        bf16x8 A[8];
#pragma unroll
        for (int ct = 0; ct < 8; ct++) A[ct] = Ap[ct * 64];
#pragma unroll
        for (int ct = 0; ct < 8; ct++)
            acc[ct] = __builtin_amdgcn_mfma_f32_16x16x32_bf16(A[ct], B, acc[ct], 0, 0, 0);
    }

    int px = pxb + cl16;
    int h = h0 + (px >> 3), w = w0 + (px & 7);
    size_t spi = ((size_t)(n * H_) + h) * W_ + w;   // spatial NHWC row index
#pragma unroll
    for (int ct = 0; ct < 8; ct++) {
        int co0 = ct * 16 + q * 4;
        float cf[4];
#pragma unroll
        for (int r = 0; r < 4; r++)
            cf[r] = coef[(size_t)(n * C_ + co0 + r) * HW_ + h * W_ + w];
        short4 fb, pb;
        float f0 = acc[ct][0] + refine_b[co0 + 0];
        float f1 = acc[ct][1] + refine_b[co0 + 1];
        float f2_ = acc[ct][2] + refine_b[co0 + 2];
        float f3 = acc[ct][3] + refine_b[co0 + 3];
        fb.x = f2bf(f0);  fb.y = f2bf(f1);  fb.z = f2bf(f2_);  fb.w = f2bf(f3);
        pb.x = f2bf(f0 + cf[0]); pb.y = f2bf(f1 + cf[1]);
        pb.z = f2bf(f2_ + cf[2]); pb.w = f2bf(f3 + cf[3]);
        *(short4*)(fusedbf + spi * 128 + co0) = fb;
        *(short4*)(pbf + spi * 128 + co0) = pb;
    }
}

// ---------------- kernel 3 (MFMA): out = gate(sigmoid(conv3x3(p))) ----------------
#define CIP 136   // 272 B row = 17 x 16B granules -> conflict-free b128
__global__ __launch_bounds__(256, 3) void k_out(const float* __restrict__ coef,
                                                const short* __restrict__ fusedbf,
                                                const short* __restrict__ pbf,
                                                const short* __restrict__ jwf,
                                                const float* __restrict__ joint_b,
                                                float* __restrict__ out) {
    __shared__ short p_s[180 * CIP];    // [(row*18+col)][ci], rows 10, cols 18
    int tid = threadIdx.x;
    int n = blockIdx.z;
    int h0 = blockIdx.y * 8, w0 = blockIdx.x * 16;

    // stage pbf (NHWC bf16): coalesced uint4 loads -> aligned b128 LDS writes
#pragma unroll
    for (int it = 0; it < 12; it++) {
        int e = it * 256 + tid;
        if (e < 2880) {
            int sp = e >> 4, g = e & 15;
            int row = sp / 18, col = sp - row * 18;
            int gh = h0 + row - 1, gw = w0 + col - 1;
            uint4 v = {0u, 0u, 0u, 0u};
            if (gh >= 0 && gh < H_ && gw >= 0 && gw < W_)
                v = *(const uint4*)(pbf + (((size_t)n * H_ + gh) * W_ + gw) * 128 + g * 8);
            *(uint4*)(p_s + sp * CIP + g * 8) = v;
        }
    }
    __syncthreads();

    int lane = tid & 63;
    int wave = __builtin_amdgcn_readfirstlane(tid >> 6);
    int c = lane & 15;
    int q = lane >> 4;
    int py0 = wave;
    int py1 = wave + 4;

    floatx4 acc[8][2];
#pragma unroll
    for (int ct = 0; ct < 8; ct++)
#pragma unroll
        for (int p = 0; p < 2; p++)
            acc[ct][p] = (floatx4){0.f, 0.f, 0.f, 0.f};

    const bf16x8* jwv = (const bf16x8*)jwf;

    for (int t = 0; t < 9; t++) {
        int dy = t / 3, dx = t - dy * 3;
        int sb0 = ((py0 + dy) * 18 + c + dx) * CIP + q * 8;
        int sb1 = ((py1 + dy) * 18 + c + dx) * CIP + q * 8;
#pragma unroll
        for (int cic = 0; cic < 4; cic++) {
            bf16x8 B0 = *(const bf16x8*)(p_s + sb0 + cic * 32);
            bf16x8 B1 = *(const bf16x8*)(p_s + sb1 + cic * 32);
            const bf16x8* Ap = jwv + ((t * 4 + cic) * 8) * 64 + lane;
            bf16x8 A[8];
#pragma unroll
            for (int ct = 0; ct < 8; ct++) A[ct] = Ap[ct * 64];
#pragma unroll
            for (int ct = 0; ct < 8; ct++) {
                acc[ct][0] = __builtin_amdgcn_mfma_f32_16x16x32_bf16(A[ct], B0, acc[ct][0], 0, 0, 0);
                acc[ct][1] = __builtin_amdgcn_mfma_f32_16x16x32_bf16(A[ct], B1, acc[ct][1], 0, 0, 0);
            }
        }
    }

    int w = w0 + c;
#pragma unroll
    for (int p = 0; p < 2; p++) {
        int h = h0 + (p == 0 ? py0 : py1);
        size_t spi = ((size_t)(n * H_) + h) * W_ + w;
#pragma unroll
        for (int ct = 0; ct < 8; ct++) {
            int co0 = ct * 16 + q * 4;
            short4 fb = *(const short4*)(fusedbf + spi * 128 + co0);
            float fv[4] = {bf2f(fb.x), bf2f(fb.y), bf2f(fb.z), bf2f(fb.w)};
#pragma unroll
            for (int r = 0; r < 4; r++) {
                int co = co0 + r;
                size_t idx = (size_t)(n * C_ + co) * HW_ + h * W_ + w;
                float z = acc[ct][p][r] + joint_b[co];
                float p2 = 1.f / (1.f + __expf(-z));
                float f = fv[r], cf = coef[idx];
                out[idx] = f + p2 * (cf - f);
            }
        }
    }
}

extern "C" void kernel_launch(void* const* d_in, const int* in_sizes, int n_in,
                              void* d_out, int out_size, void* d_ws, size_t ws_size,
                              hipStream_t stream) {
    const float* coef     = (const float*)d_in[0];
    const float* ms       = (const float*)d_in[1];
    const float* fix_w    = (const float*)d_in[2];
    const float* bn1_g    = (const float*)d_in[3];
    const float* bn1_b    = (const float*)d_in[4];
    const float* bn1_m    = (const float*)d_in[5];
    const float* bn1_v    = (const float*)d_in[6];
    const float* dyn_w    = (const float*)d_in[7];
    const float* dyn_b    = (const float*)d_in[8];
    const float* bn2_g    = (const float*)d_in[9];
    const float* bn2_b    = (const float*)d_in[10];
    const float* bn2_m    = (const float*)d_in[11];
    const float* bn2_v    = (const float*)d_in[12];
    const float* refine_w = (const float*)d_in[13];
    const float* refine_b = (const float*)d_in[14];
    const float* joint_w  = (const float*)d_in[15];
    const float* joint_b  = (const float*)d_in[16];
    float* out = (float*)d_out;

    short* fusedbf = (short*)d_ws;                          // 33554432 bf16
    short* pbf     = fusedbf + (size_t)N_ * C_ * HW_;       // 33554432 bf16
    float* dk      = (float*)(pbf + (size_t)N_ * C_ * HW_); // 2359296 f32
    short* jwf     = (short*)(dk + (size_t)N_ * 9 * HW_);   // 147456 bf16
    short* rwf     = jwf + 147456;                          // 32768 bf16

    dim3 blk(256);
    k_prep<<<dim3(576), blk, 0, stream>>>(refine_w, joint_w, rwf, jwf);
    k_dyn<<<dim3(16, 16, 4), blk, 0, stream>>>(ms, dyn_w, dyn_b, dk);
    k_fused<<<dim3(32, 32, 4), blk, 0, stream>>>(ms, dk, coef, fix_w,
                                                 bn1_g, bn1_b, bn1_m, bn1_v,
                                                 bn2_g, bn2_b, bn2_m, bn2_v,
                                                 rwf, refine_b, fusedbf, pbf);
    k_out<<<dim3(16, 32, 4), blk, 0, stream>>>(coef, fusedbf, pbf, jwf, joint_b, out);
}